// Round 4
// baseline (630.472 us; speedup 1.0000x reference)
//
#include <hip/hip_runtime.h>
#include <stdint.h>

#define N_PART   100000
#define N_FRAMES 500
#define FPW      16           // frames per packed word (2 bits/frame)
#define NW       32           // ceil(500/16); last chunk holds 4 frames

__device__ __forceinline__ uint32_t rotl32(uint32_t v, int d) {
    return (v << d) | (v >> (32 - d));
}

// JAX threefry2x32, 20 rounds, exact port of jax/_src/prng.py
#define TF_ROUND(r) { x0 += x1; x1 = rotl32(x1, (r)); x1 ^= x0; }

__device__ __forceinline__ void tf2x32(uint32_t k0, uint32_t k1,
                                       uint32_t x0, uint32_t x1,
                                       uint32_t &o0, uint32_t &o1) {
    const uint32_t k2 = k0 ^ k1 ^ 0x1BD11BDAu;
    x0 += k0; x1 += k1;
    TF_ROUND(13) TF_ROUND(15) TF_ROUND(26) TF_ROUND(6)
    x0 += k1; x1 += k2 + 1u;
    TF_ROUND(17) TF_ROUND(29) TF_ROUND(16) TF_ROUND(24)
    x0 += k2; x1 += k0 + 2u;
    TF_ROUND(13) TF_ROUND(15) TF_ROUND(26) TF_ROUND(6)
    x0 += k0; x1 += k1 + 3u;
    TF_ROUND(17) TF_ROUND(29) TF_ROUND(16) TF_ROUND(24)
    x0 += k1; x1 += k2 + 4u;
    TF_ROUND(13) TF_ROUND(15) TF_ROUND(26) TF_ROUND(6)
    x0 += k2; x1 += k0 + 5u;
    o0 = x0; o1 = x1;
}

// partitionable random_bits(key,32,shape): bits[idx] = o0^o1 of tf(key,(0,idx))
__device__ __forceinline__ float uniform_from_bits(uint32_t bits) {
    return __uint_as_float((bits >> 9) | 0x3f800000u) - 1.0f;
}

// Per-frame map m (2 bits): bit0 = next-state from s=0, bit1 = next-state from s=1.
// next(s) = (m >> s) & 1.  Identity = 0b10.
// compose(later m2, earlier m1): s -> m2(m1(s))
__device__ __forceinline__ uint32_t compose_map(uint32_t m2, uint32_t m1) {
    const uint32_t a = (m2 >> (m1 & 1u)) & 1u;
    const uint32_t b = (m2 >> ((m1 >> 1) & 1u)) & 1u;
    return a | (b << 1);
}

// Kernel A: compute packed per-frame maps + per-chunk composed maps.
// grid = (ceil(N/256), NW); thread (n, w) handles frames [w*FPW, w*FPW+16)
__global__ __launch_bounds__(256)
void map_kernel(const int* __restrict__ seed_ptr,
                uint32_t* __restrict__ words,   // [NW][N_PART]
                uint8_t* __restrict__ cmap) {   // [NW][N_PART]
    __shared__ uint32_t sk0[FPW], sk1[FPW];
    __shared__ float sp_;

    const int w   = blockIdx.y;
    const int tid = threadIdx.x;
    const uint32_t seed_lo = (uint32_t)seed_ptr[0];

    if (tid < FPW) {
        // split(key(seed)) foldlike: ks = tf(key,(0,1)); keys[t] = tf(ks,(0,t))
        uint32_t ks0, ks1, a, b;
        tf2x32(0u, seed_lo, 0u, 1u, ks0, ks1);
        tf2x32(ks0, ks1, 0u, (uint32_t)(w * FPW + tid), a, b);
        sk0[tid] = a; sk1[tid] = b;
    }
    if (tid == 32) {
        uint32_t kp0, kp1, b0, b1;
        tf2x32(0u, seed_lo, 0u, 0u, kp0, kp1);
        tf2x32(kp0, kp1, 0u, 0u, b0, b1);
        sp_ = uniform_from_bits(b0 ^ b1) * 0.001f;
    }
    __syncthreads();

    const int n = blockIdx.x * blockDim.x + tid;
    if (n >= N_PART) return;

    const float p = sp_;
    const uint32_t base = 2u * (uint32_t)n;
    const int nf = min(FPW, N_FRAMES - w * FPW);  // 16, or 4 for w=31

    uint32_t word = 0u;
    uint32_t cm = 2u;  // identity
    for (int f = 0; f < FPW; ++f) {
        uint32_t m;
        if (f < nf) {   // block-uniform branch
            uint32_t a0, a1, b0, b1;
            tf2x32(sk0[f], sk1[f], 0u, base,      a0, a1);  // u at flat idx 2n
            tf2x32(sk0[f], sk1[f], 0u, base + 1u, b0, b1);  // u at flat idx 2n+1
            const float u0 = uniform_from_bits(a0 ^ a1);
            const float u1 = uniform_from_bits(b0 ^ b1);
            const uint32_t A0 = (u0 < 0.2f) ? 1u : 0u;  // next from s=0
            const uint32_t B1 = (u1 < p)    ? 0u : 1u;  // next from s=1 (flip if hit)
            m = A0 | (B1 << 1);
        } else {
            m = 2u;  // identity padding
        }
        word |= m << (2 * f);
        cm = compose_map(m, cm);
    }
    words[(size_t)w * N_PART + n] = word;
    cmap [(size_t)w * N_PART + n] = (uint8_t)cm;
}

// Kernel B: compose preceding chunk maps -> entry state, then emit 16 frames.
__global__ __launch_bounds__(256)
void emit_kernel(const float* __restrict__ initial,
                 const uint32_t* __restrict__ words,
                 const uint8_t* __restrict__ cmap,
                 float* __restrict__ out) {
    const int w   = blockIdx.y;
    const int tid = threadIdx.x;
    const int n   = blockIdx.x * blockDim.x + tid;
    if (n >= N_PART) return;

    uint32_t s = (initial[2 * n + 1] > 0.5f) ? 1u : 0u;
    for (int j = 0; j < w; ++j)                    // loads prefetchable (addr indep of s)
        s = ((uint32_t)cmap[(size_t)j * N_PART + n] >> s) & 1u;

    const uint32_t word = words[(size_t)w * N_PART + n];
    float2* __restrict__ outv = (float2*)out;
    const float2 oh0 = make_float2(1.0f, 0.0f);
    const float2 oh1 = make_float2(0.0f, 1.0f);
    const int t0 = w * FPW;
    const int nf = min(FPW, N_FRAMES - t0);

    #pragma unroll
    for (int f = 0; f < FPW; ++f) {
        if (f < nf) {
            s = (word >> (2 * f + s)) & 1u;
            outv[(size_t)(t0 + f) * N_PART + n] = s ? oh1 : oh0;
        }
    }
}

extern "C" void kernel_launch(void* const* d_in, const int* in_sizes, int n_in,
                              void* d_out, int out_size, void* d_ws, size_t ws_size,
                              hipStream_t stream) {
    const float* initial = (const float*)d_in[0];
    const int*   seed    = (const int*)d_in[1];
    float*       out     = (float*)d_out;

    uint32_t* words = (uint32_t*)d_ws;                       // 12.8 MB
    uint8_t*  cmap  = (uint8_t*)(words + (size_t)NW * N_PART); // 3.2 MB

    const int block = 256;
    dim3 grid((N_PART + block - 1) / block, NW);
    map_kernel <<<grid, block, 0, stream>>>(seed, words, cmap);
    emit_kernel<<<grid, block, 0, stream>>>(initial, words, cmap, out);
}

// Round 6
// 563.045 us; speedup vs baseline: 1.1198x; 1.1198x over previous
//
#include <hip/hip_runtime.h>
#include <stdint.h>

#define N_PART   100000
#define N_FRAMES 500
#define NTW      16          // ceil(500/32) u32 words of packed t-bits
#define PPB      391         // particles per block; 256 blocks * 391 >= 100000

typedef float f32x4 __attribute__((ext_vector_type(4)));

__device__ __forceinline__ uint32_t rotl32(uint32_t v, int d) {
    return (v << d) | (v >> (32 - d));
}

// JAX threefry2x32, 20 rounds, exact port of jax/_src/prng.py
#define TF_ROUND(r) { x0 += x1; x1 = rotl32(x1, (r)); x1 ^= x0; }

__device__ __forceinline__ void tf2x32(uint32_t k0, uint32_t k1,
                                       uint32_t x0, uint32_t x1,
                                       uint32_t &o0, uint32_t &o1) {
    const uint32_t k2 = k0 ^ k1 ^ 0x1BD11BDAu;
    x0 += k0; x1 += k1;
    TF_ROUND(13) TF_ROUND(15) TF_ROUND(26) TF_ROUND(6)
    x0 += k1; x1 += k2 + 1u;
    TF_ROUND(17) TF_ROUND(29) TF_ROUND(16) TF_ROUND(24)
    x0 += k2; x1 += k0 + 2u;
    TF_ROUND(13) TF_ROUND(15) TF_ROUND(26) TF_ROUND(6)
    x0 += k0; x1 += k1 + 3u;
    TF_ROUND(17) TF_ROUND(29) TF_ROUND(16) TF_ROUND(24)
    x0 += k1; x1 += k2 + 4u;
    TF_ROUND(13) TF_ROUND(15) TF_ROUND(26) TF_ROUND(6)
    x0 += k2; x1 += k0 + 5u;
    o0 = x0; o1 = x1;
}

// partitionable random_bits(key,32,shape): bits[idx] = o0^o1 of tf(key,(0,idx))
__device__ __forceinline__ float uniform_from_bits(uint32_t bits) {
    return __uint_as_float((bits >> 9) | 0x3f800000u) - 1.0f;
}

// Kernel A: serial chain per particle, emits packed state bitmap.
// grid = 256 blocks x 512 threads; block b owns particles [b*PPB, b*PPB+PPB)
// bmp layout: word (tw, n) at bmp[tw*N_PART + n]; bit (t&31) = state after frame t.
__global__ __launch_bounds__(512)
void chain_kernel(const float* __restrict__ initial,
                  const int* __restrict__ seed_ptr,
                  uint32_t* __restrict__ bmp) {
    __shared__ uint32_t sk0[N_FRAMES + 1], sk1[N_FRAMES + 1];
    __shared__ float sp_;

    const int tid = threadIdx.x;
    const uint32_t seed_lo = (uint32_t)seed_ptr[0];

    if (tid <= N_FRAMES) {
        // split(key(seed)) foldlike: ks = tf(key,(0,1)); keys[t] = tf(ks,(0,t))
        uint32_t ks0, ks1, a, b;
        tf2x32(0u, seed_lo, 0u, 1u, ks0, ks1);
        tf2x32(ks0, ks1, 0u, (uint32_t)tid, a, b);   // tid==500 -> prefetch pad
        sk0[tid] = a; sk1[tid] = b;
    }
    if (tid == 511) {
        uint32_t kp0, kp1, b0, b1;
        tf2x32(0u, seed_lo, 0u, 0u, kp0, kp1);
        tf2x32(kp0, kp1, 0u, 0u, b0, b1);
        sp_ = uniform_from_bits(b0 ^ b1) * 0.001f;
    }
    __syncthreads();

    const int n = blockIdx.x * PPB + tid;
    if (tid >= PPB || n >= N_PART) return;

    const float p  = sp_;
    const float p0 = 0.2f;
    const uint32_t base = 2u * (uint32_t)n;

    uint32_t s = (initial[2 * n + 1] > 0.5f) ? 1u : 0u;
    uint32_t k0 = sk0[0], k1 = sk1[0];
    uint32_t bits = 0u;

    for (int t = 0; t < N_FRAMES; ++t) {
        const uint32_t nk0 = sk0[t + 1], nk1 = sk1[t + 1];  // prefetch next key
        uint32_t o0, o1;
        tf2x32(k0, k1, 0u, base + s, o0, o1);
        const float u = uniform_from_bits(o0 ^ o1);
        s ^= (u < (s ? p : p0)) ? 1u : 0u;
        bits |= s << (t & 31);
        if ((t & 31) == 31) {
            bmp[(size_t)(t >> 5) * N_PART + n] = bits;
            bits = 0u;
        }
        k0 = nk0; k1 = nk1;
    }
    bmp[(size_t)(NTW - 1) * N_PART + n] = bits;   // word 15: t=480..499 (20 bits)
}

// Kernel B: fill-shaped expansion. Linear sweep of output as float4
// (one float4 = 2 particles at one frame). Bitmap reads are contiguous
// 512 B/wave and L2-resident; output stores nontemporal, 1 KB/wave chunks.
__global__ __launch_bounds__(256)
void emit_kernel(const uint32_t* __restrict__ bmp,
                 f32x4* __restrict__ out4) {
    const int total = (N_FRAMES * N_PART) / 2;          // 2.5e7 float4
    const int stride = gridDim.x * blockDim.x;
    for (int f = blockIdx.x * blockDim.x + threadIdx.x; f < total; f += stride) {
        const unsigned t  = (unsigned)f / (N_PART / 2); // magic-mul
        const unsigned rr = (unsigned)f - t * (N_PART / 2);
        const unsigned n0 = 2u * rr;                    // particles n0, n0+1
        const size_t wbase = (size_t)(t >> 5) * N_PART + n0;
        const uint32_t w0 = bmp[wbase];
        const uint32_t w1 = bmp[wbase + 1];
        const uint32_t bit = t & 31u;
        const float s0 = (float)((w0 >> bit) & 1u);
        const float s1 = (float)((w1 >> bit) & 1u);
        f32x4 v;
        v.x = 1.0f - s0; v.y = s0; v.z = 1.0f - s1; v.w = s1;
        __builtin_nontemporal_store(v, &out4[f]);
    }
}

extern "C" void kernel_launch(void* const* d_in, const int* in_sizes, int n_in,
                              void* d_out, int out_size, void* d_ws, size_t ws_size,
                              hipStream_t stream) {
    const float* initial = (const float*)d_in[0];
    const int*   seed    = (const int*)d_in[1];
    uint32_t*    bmp     = (uint32_t*)d_ws;      // 16 * 100000 * 4 B = 6.4 MB
    f32x4*       out4    = (f32x4*)d_out;

    chain_kernel<<<256, 512, 0, stream>>>(initial, seed, bmp);
    emit_kernel<<<4096, 256, 0, stream>>>(bmp, out4);
}